// Round 3
// baseline (98.051 us; speedup 1.0000x reference)
//
#include <hip/hip_runtime.h>

// out[n][o] = sum_{s,i} tanh(slope[s][i][o]*x[n][i] - thres[s][i][o]) * ampli[s][i][o]^2
// N_DATA=128, N_SYN=8, IN_DIM=784, OUT_DIM=128

#define N_DATA  128
#define N_SYN   8
#define IN_DIM  784
#define OUT_DIM 128

#define NTILE   32    // n per block
#define NACC    16    // n per thread (2 nsub halves per block)
#define ICHUNK  56    // i per block
#define NICHUNK 14    // 784 / 56
#define NTILES  4     // 128 / 32

__global__ __launch_bounds__(256)
void psl_kernel(const float* __restrict__ x,      // [128][784]
                const float* __restrict__ thres,  // [8][784][128]
                const float* __restrict__ slope,  // [8][784][128]
                const float* __restrict__ ampli,  // [8][784][128]
                float* __restrict__ out)          // [128][128]
{
    const int t    = threadIdx.x;
    const int o    = t & 127;       // lane->o, coalesced param loads
    const int nsub = t >> 7;        // 0/1, wave-uniform

    int bid = blockIdx.x;
    const int ic    = bid % NICHUNK; bid /= NICHUNK;
    const int s     = bid % N_SYN;   bid /= N_SYN;
    const int ntile = bid;           // 0..3

    const int i0    = ic * ICHUNK;
    const int nbase = ntile * NTILE + nsub * NACC;

    // x tile staged in LDS: [i][n], 56*32*4 = 7 KB, rows 128B-aligned for float4
    __shared__ float xs[ICHUNK][NTILE];

    // cooperative load: consecutive threads -> consecutive n -> conflict-free LDS write
    for (int idx = t; idx < ICHUNK * NTILE; idx += 256) {
        const int nl = idx & (NTILE - 1);
        const int il = idx >> 5;
        xs[il][nl] = x[(ntile * NTILE + nl) * IN_DIM + i0 + il];
    }
    __syncthreads();

    float acc[NACC];
#pragma unroll
    for (int k = 0; k < NACC; ++k) acc[k] = 0.f;
    float suma2 = 0.f;

    const float C = 2.8853900817779268f;  // 2*log2(e)
    const int pbase = (s * IN_DIM + i0) * OUT_DIM + o;

    for (int il = 0; il < ICHUNK; ++il) {
        const int pidx = pbase + il * OUT_DIM;
        const float sl = slope[pidx];
        const float th = thres[pidx];
        const float am = ampli[pidx];

        const float a2   = am * am;
        suma2 += a2;                       // n-independent term, hoisted
        const float m2a2 = -2.f * a2;
        const float slC  = sl * C;
        const float thC  = th * C;

        // broadcast float4 reads (same address across all lanes -> conflict-free)
        const float4* xrow = reinterpret_cast<const float4*>(&xs[il][nsub * NACC]);
#pragma unroll
        for (int q = 0; q < 4; ++q) {
            const float4 xv = xrow[q];
            {
                float z = __builtin_fmaf(slC, xv.x, -thC);
                float r = __builtin_amdgcn_rcpf(__builtin_amdgcn_exp2f(z) + 1.f);
                acc[4*q+0] = __builtin_fmaf(m2a2, r, acc[4*q+0]);
            }
            {
                float z = __builtin_fmaf(slC, xv.y, -thC);
                float r = __builtin_amdgcn_rcpf(__builtin_amdgcn_exp2f(z) + 1.f);
                acc[4*q+1] = __builtin_fmaf(m2a2, r, acc[4*q+1]);
            }
            {
                float z = __builtin_fmaf(slC, xv.z, -thC);
                float r = __builtin_amdgcn_rcpf(__builtin_amdgcn_exp2f(z) + 1.f);
                acc[4*q+2] = __builtin_fmaf(m2a2, r, acc[4*q+2]);
            }
            {
                float z = __builtin_fmaf(slC, xv.w, -thC);
                float r = __builtin_amdgcn_rcpf(__builtin_amdgcn_exp2f(z) + 1.f);
                acc[4*q+3] = __builtin_fmaf(m2a2, r, acc[4*q+3]);
            }
        }
    }

    // tanh*a2 = a2 - 2*a2*r ; the "+a2 per i" part is suma2, added once here
#pragma unroll
    for (int k = 0; k < NACC; ++k) {
        atomicAdd(&out[(nbase + k) * OUT_DIM + o], acc[k] + suma2);
    }
}

extern "C" void kernel_launch(void* const* d_in, const int* in_sizes, int n_in,
                              void* d_out, int out_size, void* d_ws, size_t ws_size,
                              hipStream_t stream) {
    const float* x     = (const float*)d_in[0];
    const float* thres = (const float*)d_in[1];
    const float* slope = (const float*)d_in[2];
    const float* ampli = (const float*)d_in[3];
    float* out = (float*)d_out;

    // harness poisons d_out with 0xAA before every launch; we accumulate atomically
    hipMemsetAsync(out, 0, (size_t)out_size * sizeof(float), stream);

    const int nblocks = NTILES * N_SYN * NICHUNK;  // 4*8*14 = 448
    psl_kernel<<<nblocks, 256, 0, stream>>>(x, thres, slope, ampli, out);
}